// Round 4
// baseline (197.922 us; speedup 1.0000x reference)
//
#include <hip/hip_runtime.h>
#include <hip/hip_fp16.h>
#include <stdint.h>

// deform_conv2d: N=8, C=256, H=W=64, OC=256, 3x3, stride=1, pad=1 -> OH=OW=64
// im2col-fused MFMA GEMM. M=32768 (n,oh,ow), N=256 oc, K=2304 (kd = k*256+c).
// R10: occupancy restore. R9 showed MfmaUtil invariant at ~22% across 3
//   schedules; per-chunk pipe math (MFMA ~1240 cyc/SIMD, VMEM ~1300 cyc/CU,
//   wall 4400) => latency-exposed at 2 waves/SIMD (1 block/CU). R10 keeps
//   R9's reg-B + LDS-only-A structure but returns to 512 blocks (2/CU),
//   tile 64 rows x 256 oc, wave 32x64 (acc[2][4]), 1 staging unit/thread.
//   LDS 2x8KB=16KB; VGPR ~110 < 128 cap => 16 waves/CU; the two co-resident
//   blocks run barrier-out-of-phase so MFMA of one covers gather latency +
//   vmcnt(0) drain of the other (R8's proven overlap, on half the traffic).

typedef _Float16 half8 __attribute__((ext_vector_type(8)));
typedef float f32x4 __attribute__((ext_vector_type(4)));

__device__ __forceinline__ __half2 h2(uint32_t u) {
  return __builtin_bit_cast(__half2, u);
}
__device__ __forceinline__ uint32_t packh2f(float a, float b) {
  return __builtin_bit_cast(uint32_t, __floats2half2_rn(a, b));
}
__device__ __forceinline__ __half2 duplo(uint32_t u) {
  return __half2half2(__builtin_bit_cast(__half, (unsigned short)(u & 0xffffu)));
}
__device__ __forceinline__ __half2 duphi(uint32_t u) {
  return __half2half2(__builtin_bit_cast(__half, (unsigned short)(u >> 16)));
}

// ---- merged prep: [0,2048) x NCHW fp32 -> NHWC f16
//                   [2048,4352) weights -> swizzled f16 image
//                   [4352,5504) offsets -> packed coords {4 x f16 w, 4 x u16 pix}
__global__ __launch_bounds__(256) void prep_all_kernel(
    const float* __restrict__ x, const float* __restrict__ w,
    const float* __restrict__ offset,
    unsigned short* __restrict__ xb, unsigned short* __restrict__ w3s,
    unsigned short* __restrict__ coords) {
  __shared__ float tile[64][65];
  int tid = threadIdx.x;
  if (blockIdx.x < 2048) {
    int bn   = blockIdx.x >> 8;
    int rem  = blockIdx.x & 255;
    int y    = rem >> 2;
    int cblk = rem & 3;
    const float* src = x + ((size_t)(bn * 256 + cblk * 64)) * 4096 + y * 64;
#pragma unroll
    for (int i = 0; i < 4; ++i) {
      int u  = i * 256 + tid;
      int cl = u >> 4;
      int xs = (u & 15) * 4;
      float4 v = *(const float4*)(src + cl * 4096 + xs);
      tile[cl][xs] = v.x; tile[cl][xs + 1] = v.y;
      tile[cl][xs + 2] = v.z; tile[cl][xs + 3] = v.w;
    }
    __syncthreads();
    unsigned short* dst = xb + ((size_t)(bn * 64 + y) * 64) * 256 + cblk * 64;
#pragma unroll
    for (int i = 0; i < 8; ++i) {
      int v2  = i * 256 + tid;
      int xc  = v2 >> 5;
      int cl2 = (v2 & 31) * 2;
      *(uint32_t*)(dst + xc * 256 + cl2) = packh2f(tile[cl2][xc], tile[cl2 + 1][xc]);
    }
  } else if (blockIdx.x < 4352) {
    int idx = (blockIdx.x - 2048) * 256 + tid;   // < 589824
    int t   = idx >> 14;
    int r2  = idx & 16383;
    int g   = r2 >> 3;
    int e   = r2 & 7;
    int oc  = g >> 3;
    int kk8 = (g & 7) ^ (oc & 7);
    int kk  = kk8 * 8 + e;
    int c   = (t & 3) * 64 + kk;
    int k   = t >> 2;
    w3s[idx] = __builtin_bit_cast(unsigned short, __float2half(w[(oc * 256 + c) * 9 + k]));
  } else {
    int idx = (blockIdx.x - 4352) * 256 + tid;   // < 294912
    int ow  = idx & 63;
    int oh  = (idx >> 6) & 63;
    int r   = idx >> 12;          // bn*9 + k
    int k   = r % 9;
    int bn  = r / 9;
    int ky = k / 3 - 1;
    int kx = k % 3 - 1;
    float offy = offset[((bn * 18 + 2 * k    ) * 64 + oh) * 64 + ow];
    float offx = offset[((bn * 18 + 2 * k + 1) * 64 + oh) * 64 + ow];
    float y = (float)(oh + ky) + offy;
    float x2 = (float)(ow + kx) + offx;
    float y0f = floorf(y), x0f = floorf(x2);
    float fy = y - y0f, fx = x2 - x0f;
    int y0 = (int)y0f, x0 = (int)x0f;
    int y1 = y0 + 1, x1 = x0 + 1;
    float vy0 = (y0 >= 0 && y0 <= 63) ? 1.0f : 0.0f;
    float vy1 = (y1 >= 0 && y1 <= 63) ? 1.0f : 0.0f;
    float vx0 = (x0 >= 0 && x0 <= 63) ? 1.0f : 0.0f;
    float vx1 = (x1 >= 0 && x1 <= 63) ? 1.0f : 0.0f;
    float wy0 = (1.0f - fy) * vy0, wy1 = fy * vy1;
    float wx0 = (1.0f - fx) * vx0, wx1 = fx * vx1;
    int y0c = min(max(y0, 0), 63), y1c = min(max(y1, 0), 63);
    int x0c = min(max(x0, 0), 63), x1c = min(max(x1, 0), 63);
    unsigned short ent[8];
    ent[0] = __builtin_bit_cast(unsigned short, __float2half(wy0 * wx0));
    ent[1] = __builtin_bit_cast(unsigned short, __float2half(wy0 * wx1));
    ent[2] = __builtin_bit_cast(unsigned short, __float2half(wy1 * wx0));
    ent[3] = __builtin_bit_cast(unsigned short, __float2half(wy1 * wx1));
    ent[4] = (unsigned short)(y0c * 64 + x0c);
    ent[5] = (unsigned short)(y0c * 64 + x1c);
    ent[6] = (unsigned short)(y1c * 64 + x0c);
    ent[7] = (unsigned short)(y1c * 64 + x1c);
    *(uint4*)(coords + (size_t)idx * 8) = *(const uint4*)ent;
  }
}

// ---- main: 512 blocks x 512 threads; block tile 64 rows x 256 oc; wave 32x64 ----
__global__ __launch_bounds__(512, 4) void deform_mfma_kernel(
    const unsigned short* __restrict__ xb,      // NHWC f16
    const unsigned short* __restrict__ coords,  // packed coord entries
    const unsigned short* __restrict__ w3s,     // swizzled chunk-major f16
    float* __restrict__ out) {                  // (8, 256, 64, 64) fp32
  // A-tile only; double-buffered, XOR group swizzle (no pad). 16 KB total.
  __shared__ __align__(16) unsigned short At[2][64 * 64];

  int bn  = blockIdx.x & 7;      // XCD swizzle
  int oh  = blockIdx.x >> 3;
  int tid = threadIdx.x;

  int w    = tid >> 6;            // wave 0..7
  int lane = tid & 63;
  int wrow = w & 1;               // 32-row half
  int wcol = w >> 1;              // 64-oc quarter
  int mrow = lane & 15;
  int quad = lane >> 4;

  // staging identity: one thread = one (row, 8-ch group) unit
  int srow = tid >> 3;             // 0..63
  int sg   = tid & 7;

  const char* xbc = (const char*)(xb + (size_t)bn * (64 * 64 * 256));
  const unsigned short* cb = coords + ((size_t)((bn * 9) * 64 + oh) * 64 + srow) * 8;

  int aw0  = srow * 64 + ((sg ^ (srow & 7)) * 8);   // XOR-swizzled slot (shorts)
  int grp0 = quad ^ (mrow & 7);                     // ks=0 frag group
  int grp1 = (4 + quad) ^ (mrow & 7);               // ks=1 frag group
  int a_base = (wrow * 32 + mrow) * 64;             // + m*1024 (shorts)
  int boff0 = ((wcol * 64 + mrow) * 8 + grp0) * 16; // bytes into w3s chunk
  int boff1 = ((wcol * 64 + mrow) * 8 + grp1) * 16; // (+ nn*2048)

  f32x4 acc[2][4] = {};
  half8 bA[2][4], bB[2][4];

  __half2 w00, w01, w02, w03;
  uint32_t o00, o01, o02, o03;
  uint4 cn;

  // B frags straight from w3s (fragment-ordered by prep; L1/L2-resident)
#define BLOADR(TT, BS)                                                          \
  {                                                                             \
    const char* wp = (const char*)w3s + (size_t)(TT) * 32768;                   \
    _Pragma("unroll")                                                           \
    for (int nn = 0; nn < 4; ++nn) {                                            \
      BS[0][nn] = *(const half8*)(wp + boff0 + nn * 2048);                      \
      BS[1][nn] = *(const half8*)(wp + boff1 + nn * 2048);                      \
    }                                                                           \
  }

#define TAPSETUP_R(CE)                                                          \
  {                                                                             \
    w00 = duplo((CE).x); w01 = duphi((CE).x);                                   \
    w02 = duplo((CE).y); w03 = duphi((CE).y);                                   \
    o00 = (((CE).z & 0xffffu) << 9) + sg * 16;                                  \
    o01 = (((CE).z >> 16) << 9) + sg * 16;                                      \
    o02 = (((CE).w & 0xffffu) << 9) + sg * 16;                                  \
    o03 = (((CE).w >> 16) << 9) + sg * 16;                                      \
  }

  // one 16B bilinear unit per thread, packed-f16 math
#define ASTAGE(TT, ATP)                                                         \
  {                                                                             \
    uint4 c0 = *(const uint4*)(xbc + o00 + ((TT) & 3) * 128);                   \
    uint4 c1 = *(const uint4*)(xbc + o01 + ((TT) & 3) * 128);                   \
    uint4 c2 = *(const uint4*)(xbc + o02 + ((TT) & 3) * 128);                   \
    uint4 c3 = *(const uint4*)(xbc + o03 + ((TT) & 3) * 128);                   \
    __half2 r0 = __hmul2(h2(c0.x), w00);                                        \
    r0 = __hfma2(h2(c1.x), w01, r0); r0 = __hfma2(h2(c2.x), w02, r0);           \
    r0 = __hfma2(h2(c3.x), w03, r0);                                            \
    __half2 r1 = __hmul2(h2(c0.y), w00);                                        \
    r1 = __hfma2(h2(c1.y), w01, r1); r1 = __hfma2(h2(c2.y), w02, r1);           \
    r1 = __hfma2(h2(c3.y), w03, r1);                                            \
    __half2 r2 = __hmul2(h2(c0.z), w00);                                        \
    r2 = __hfma2(h2(c1.z), w01, r2); r2 = __hfma2(h2(c2.z), w02, r2);           \
    r2 = __hfma2(h2(c3.z), w03, r2);                                            \
    __half2 r3 = __hmul2(h2(c0.w), w00);                                        \
    r3 = __hfma2(h2(c1.w), w01, r3); r3 = __hfma2(h2(c2.w), w02, r3);           \
    r3 = __hfma2(h2(c3.w), w03, r3);                                            \
    uint4 pk;                                                                   \
    pk.x = __builtin_bit_cast(uint32_t, r0);                                    \
    pk.y = __builtin_bit_cast(uint32_t, r1);                                    \
    pk.z = __builtin_bit_cast(uint32_t, r2);                                    \
    pk.w = __builtin_bit_cast(uint32_t, r3);                                    \
    *(uint4*)((ATP) + aw0) = pk;                                                \
  }

#define COMPUTE(ATP, BS)                                                        \
  {                                                                             \
    _Pragma("unroll")                                                           \
    for (int m = 0; m < 2; ++m) {                                               \
      half8 af0 = *(const half8*)((ATP) + a_base + m * 1024 + grp0 * 8);        \
      half8 af1 = *(const half8*)((ATP) + a_base + m * 1024 + grp1 * 8);        \
      _Pragma("unroll")                                                         \
      for (int nn = 0; nn < 4; ++nn) {                                          \
        acc[m][nn] = __builtin_amdgcn_mfma_f32_16x16x32_f16(af0, BS[0][nn], acc[m][nn], 0, 0, 0); \
        acc[m][nn] = __builtin_amdgcn_mfma_f32_16x16x32_f16(af1, BS[1][nn], acc[m][nn], 0, 0, 0); \
      }                                                                         \
    }                                                                           \
  }

  // prologue: tap 0 setup + stage chunk 0 (At[0], bA)
  {
    uint4 ce0 = *(const uint4*)cb;
    TAPSETUP_R(ce0)
  }
  BLOADR(0, bA)
  ASTAGE(0, &At[0][0])
  __syncthreads();

  for (int tap = 0; tap < 9; ++tap) {
#pragma unroll
    for (int cc = 0; cc < 4; ++cc) {
      const int t = tap * 4 + cc;
      // stage chunk t+1 (B -> other reg set, A -> other LDS buffer)
      if (t < 35) {
        if (cc & 1) { BLOADR(t + 1, bA) } else { BLOADR(t + 1, bB) }
        if (cc == 2 && tap < 8) cn = *(const uint4*)(cb + (tap + 1) * 32768);
        if (cc == 3) TAPSETUP_R(cn)
        if (cc & 1) { ASTAGE(t + 1, &At[0][0]) } else { ASTAGE(t + 1, &At[1][0]) }
      }
      // compute chunk t
      if (cc & 1) { COMPUTE(&At[1][0], bB) } else { COMPUTE(&At[0][0], bA) }
      __syncthreads();   // orders At swap; vmcnt(0) drain validates B regs
    }
  }

  // ---- epilogue: C/D layout col=lane&15(oc), row=quad*4+reg(ow) ----
  float* outp = out + (size_t)bn * 256 * 4096 + (size_t)oh * 64;
#pragma unroll
  for (int m = 0; m < 2; ++m) {
    int ow0 = wrow * 32 + m * 16 + quad * 4;
#pragma unroll
    for (int nn = 0; nn < 4; ++nn) {
      int oc = wcol * 64 + nn * 16 + mrow;
      *(f32x4*)(outp + (size_t)oc * 4096 + ow0) = acc[m][nn];
    }
  }
#undef BLOADR
#undef TAPSETUP_R
#undef ASTAGE
#undef COMPUTE
}

extern "C" void kernel_launch(void* const* d_in, const int* in_sizes, int n_in,
                              void* d_out, int out_size, void* d_ws, size_t ws_size,
                              hipStream_t stream) {
  (void)in_sizes; (void)n_in; (void)out_size; (void)ws_size;
  const float* x      = (const float*)d_in[0];
  const float* offset = (const float*)d_in[1];
  const float* weight = (const float*)d_in[2];
  float* out = (float*)d_out;

  unsigned short* xb     = (unsigned short*)d_ws;                        // 16.78 MB
  unsigned short* w3s    = xb + (size_t)8 * 64 * 64 * 256;               // +1.18 MB
  unsigned short* coords = w3s + (size_t)36 * 16384;                     // +4.72 MB

  prep_all_kernel<<<5504, 256, 0, stream>>>(x, weight, offset, xb, w3s, coords);
  deform_mfma_kernel<<<512, 512, 0, stream>>>(xb, coords, w3s, out);
}

// Round 5
// 155.053 us; speedup vs baseline: 1.2765x; 1.2765x over previous
//
#include <hip/hip_runtime.h>
#include <hip/hip_fp16.h>
#include <stdint.h>

// deform_conv2d: N=8, C=256, H=W=64, OC=256, 3x3, stride=1, pad=1 -> OH=OW=64
// im2col-fused MFMA GEMM. M=32768 (n,oh,ow), N=256 oc, K=2304 (kd = k*256+c).
// R11: spill-proof fusion of R8 (2 blocks/CU overlap) + R9 (reg-B, LDS-only-A).
//   R10 failed on scratch spills (WRITE 33->120 MB): double-buffered B regs +
//   launch_bounds(512,4) => allocator picked 64 VGPR and spilled per chunk.
//   Fixes: (a) SINGLE-buffered B regs (loaded at chunk start; no cross-barrier
//   B liveness; ~116 VGPR fits (512,2) honestly -- R9 precedent); (b) w3s
//   re-laid out [chunk][wcol][nn][ks][lane] so each B-frag load instruction's
//   64 lanes read a contiguous 1 KB (8 L1 segments vs 64 scattered in R10);
//   (c) T14 split staging: AGATHER(t+1) issues BEFORE COMPUTE(t) (latency
//   hides under MFMA; MFMA waits only vmcnt(4) for B), AMATH(t+1) (f16 math +
//   ds_write) after. 512 blocks x 512 thr, tile 64x256, LDS 16 KB, 1 barrier.

typedef _Float16 half8 __attribute__((ext_vector_type(8)));
typedef float f32x4 __attribute__((ext_vector_type(4)));

__device__ __forceinline__ __half2 h2(uint32_t u) {
  return __builtin_bit_cast(__half2, u);
}
__device__ __forceinline__ uint32_t packh2f(float a, float b) {
  return __builtin_bit_cast(uint32_t, __floats2half2_rn(a, b));
}
__device__ __forceinline__ __half2 duplo(uint32_t u) {
  return __half2half2(__builtin_bit_cast(__half, (unsigned short)(u & 0xffffu)));
}
__device__ __forceinline__ __half2 duphi(uint32_t u) {
  return __half2half2(__builtin_bit_cast(__half, (unsigned short)(u >> 16)));
}

// ---- merged prep: [0,2048) x NCHW fp32 -> NHWC f16
//                   [2048,4352) weights -> wave-contiguous f16 panels
//                   [4352,5504) offsets -> packed coords {4 x f16 w, 4 x u16 pix}
__global__ __launch_bounds__(256) void prep_all_kernel(
    const float* __restrict__ x, const float* __restrict__ w,
    const float* __restrict__ offset,
    unsigned short* __restrict__ xb, unsigned short* __restrict__ w3s,
    unsigned short* __restrict__ coords) {
  __shared__ float tile[64][65];
  int tid = threadIdx.x;
  if (blockIdx.x < 2048) {
    int bn   = blockIdx.x >> 8;
    int rem  = blockIdx.x & 255;
    int y    = rem >> 2;
    int cblk = rem & 3;
    const float* src = x + ((size_t)(bn * 256 + cblk * 64)) * 4096 + y * 64;
#pragma unroll
    for (int i = 0; i < 4; ++i) {
      int u  = i * 256 + tid;
      int cl = u >> 4;
      int xs = (u & 15) * 4;
      float4 v = *(const float4*)(src + cl * 4096 + xs);
      tile[cl][xs] = v.x; tile[cl][xs + 1] = v.y;
      tile[cl][xs + 2] = v.z; tile[cl][xs + 3] = v.w;
    }
    __syncthreads();
    unsigned short* dst = xb + ((size_t)(bn * 64 + y) * 64) * 256 + cblk * 64;
#pragma unroll
    for (int i = 0; i < 8; ++i) {
      int v2  = i * 256 + tid;
      int xc  = v2 >> 5;
      int cl2 = (v2 & 31) * 2;
      *(uint32_t*)(dst + xc * 256 + cl2) = packh2f(tile[cl2][xc], tile[cl2 + 1][xc]);
    }
  } else if (blockIdx.x < 4352) {
    // w3s layout: chunk t (16384 shorts) = [wcol(4)][nn(4)][ks(2)][lane(64)][e(8)]
    // frag at (wcol,nn,ks,lane): oc = wcol*64+nn*16+(lane&15), g = ks*4+(lane>>4),
    // elements kk = g*8+e; c = (t&3)*64+kk; k = t>>2.
    int idx = (blockIdx.x - 2048) * 256 + tid;   // < 589824
    int t    = idx >> 14;
    int r2   = idx & 16383;
    int e    = r2 & 7;
    int lane = (r2 >> 3) & 63;
    int ks   = (r2 >> 9) & 1;
    int nn   = (r2 >> 10) & 3;
    int wcol = (r2 >> 12) & 3;
    int oc = wcol * 64 + nn * 16 + (lane & 15);
    int kk = (ks * 4 + (lane >> 4)) * 8 + e;
    int c  = (t & 3) * 64 + kk;
    int k  = t >> 2;
    w3s[idx] = __builtin_bit_cast(unsigned short, __float2half(w[(oc * 256 + c) * 9 + k]));
  } else {
    int idx = (blockIdx.x - 4352) * 256 + tid;   // < 294912
    int ow  = idx & 63;
    int oh  = (idx >> 6) & 63;
    int r   = idx >> 12;          // bn*9 + k
    int k   = r % 9;
    int bn  = r / 9;
    int ky = k / 3 - 1;
    int kx = k % 3 - 1;
    float offy = offset[((bn * 18 + 2 * k    ) * 64 + oh) * 64 + ow];
    float offx = offset[((bn * 18 + 2 * k + 1) * 64 + oh) * 64 + ow];
    float y = (float)(oh + ky) + offy;
    float x2 = (float)(ow + kx) + offx;
    float y0f = floorf(y), x0f = floorf(x2);
    float fy = y - y0f, fx = x2 - x0f;
    int y0 = (int)y0f, x0 = (int)x0f;
    int y1 = y0 + 1, x1 = x0 + 1;
    float vy0 = (y0 >= 0 && y0 <= 63) ? 1.0f : 0.0f;
    float vy1 = (y1 >= 0 && y1 <= 63) ? 1.0f : 0.0f;
    float vx0 = (x0 >= 0 && x0 <= 63) ? 1.0f : 0.0f;
    float vx1 = (x1 >= 0 && x1 <= 63) ? 1.0f : 0.0f;
    float wy0 = (1.0f - fy) * vy0, wy1 = fy * vy1;
    float wx0 = (1.0f - fx) * vx0, wx1 = fx * vx1;
    int y0c = min(max(y0, 0), 63), y1c = min(max(y1, 0), 63);
    int x0c = min(max(x0, 0), 63), x1c = min(max(x1, 0), 63);
    unsigned short ent[8];
    ent[0] = __builtin_bit_cast(unsigned short, __float2half(wy0 * wx0));
    ent[1] = __builtin_bit_cast(unsigned short, __float2half(wy0 * wx1));
    ent[2] = __builtin_bit_cast(unsigned short, __float2half(wy1 * wx0));
    ent[3] = __builtin_bit_cast(unsigned short, __float2half(wy1 * wx1));
    ent[4] = (unsigned short)(y0c * 64 + x0c);
    ent[5] = (unsigned short)(y0c * 64 + x1c);
    ent[6] = (unsigned short)(y1c * 64 + x0c);
    ent[7] = (unsigned short)(y1c * 64 + x1c);
    *(uint4*)(coords + (size_t)idx * 8) = *(const uint4*)ent;
  }
}

// ---- main: 512 blocks x 512 threads; block tile 64 rows x 256 oc; wave 32x64 ----
__global__ __launch_bounds__(512, 2) void deform_mfma_kernel(
    const unsigned short* __restrict__ xb,      // NHWC f16
    const unsigned short* __restrict__ coords,  // packed coord entries
    const unsigned short* __restrict__ w3s,     // wave-contiguous panels f16
    float* __restrict__ out) {                  // (8, 256, 64, 64) fp32
  // A-tile only; double-buffered, XOR group swizzle (no pad). 16 KB total.
  __shared__ __align__(16) unsigned short At[2][64 * 64];

  int bn  = blockIdx.x & 7;      // XCD swizzle
  int oh  = blockIdx.x >> 3;
  int tid = threadIdx.x;

  int w    = tid >> 6;            // wave 0..7
  int lane = tid & 63;
  int wrow = w & 1;               // 32-row half
  int wcol = w >> 1;              // 64-oc quarter
  int mrow = lane & 15;
  int quad = lane >> 4;

  // staging identity: one thread = one (row, 8-ch group) unit
  int srow = tid >> 3;             // 0..63
  int sg   = tid & 7;

  const char* xbc = (const char*)(xb + (size_t)bn * (64 * 64 * 256));
  const unsigned short* cb = coords + ((size_t)((bn * 9) * 64 + oh) * 64 + srow) * 8;

  int aw0  = srow * 64 + ((sg ^ (srow & 7)) * 8);   // XOR-swizzled slot (shorts)
  int grp0 = quad ^ (mrow & 7);                     // ks=0 A frag group
  int grp1 = (4 + quad) ^ (mrow & 7);               // ks=1 A frag group
  int a_base = (wrow * 32 + mrow) * 64;             // + m*1024 (shorts)
  int b_off  = wcol * 8192 + lane * 16;             // bytes; + (nn*2+ks)*1024

  f32x4 acc[2][4] = {};
  half8 bC[2][4];

  __half2 w00, w01, w02, w03;
  uint32_t o00, o01, o02, o03;
  uint4 cn, gc0, gc1, gc2, gc3;

  // B frags straight from w3s: each load = contiguous 1 KB across the wave
#define BLOADR(TT, BS)                                                          \
  {                                                                             \
    const char* wp = (const char*)w3s + (size_t)(TT) * 32768 + b_off;           \
    _Pragma("unroll")                                                           \
    for (int nn = 0; nn < 4; ++nn) {                                            \
      BS[0][nn] = *(const half8*)(wp + (nn * 2 + 0) * 1024);                    \
      BS[1][nn] = *(const half8*)(wp + (nn * 2 + 1) * 1024);                    \
    }                                                                           \
  }

#define TAPSETUP_R(CE)                                                          \
  {                                                                             \
    w00 = duplo((CE).x); w01 = duphi((CE).x);                                   \
    w02 = duplo((CE).y); w03 = duphi((CE).y);                                   \
    o00 = (((CE).z & 0xffffu) << 9) + sg * 16;                                  \
    o01 = (((CE).z >> 16) << 9) + sg * 16;                                      \
    o02 = (((CE).w & 0xffffu) << 9) + sg * 16;                                  \
    o03 = (((CE).w >> 16) << 9) + sg * 16;                                      \
  }

  // issue the 4 corner gathers (latency hides under COMPUTE)
#define AGATHER(TT)                                                             \
  {                                                                             \
    gc0 = *(const uint4*)(xbc + o00 + ((TT) & 3) * 128);                        \
    gc1 = *(const uint4*)(xbc + o01 + ((TT) & 3) * 128);                        \
    gc2 = *(const uint4*)(xbc + o02 + ((TT) & 3) * 128);                        \
    gc3 = *(const uint4*)(xbc + o03 + ((TT) & 3) * 128);                        \
  }

  // packed-f16 bilinear combine + LDS write (after COMPUTE, before barrier)
#define AMATH(ATP)                                                              \
  {                                                                             \
    __half2 r0 = __hmul2(h2(gc0.x), w00);                                       \
    r0 = __hfma2(h2(gc1.x), w01, r0); r0 = __hfma2(h2(gc2.x), w02, r0);         \
    r0 = __hfma2(h2(gc3.x), w03, r0);                                           \
    __half2 r1 = __hmul2(h2(gc0.y), w00);                                       \
    r1 = __hfma2(h2(gc1.y), w01, r1); r1 = __hfma2(h2(gc2.y), w02, r1);         \
    r1 = __hfma2(h2(gc3.y), w03, r1);                                           \
    __half2 r2 = __hmul2(h2(gc0.z), w00);                                       \
    r2 = __hfma2(h2(gc1.z), w01, r2); r2 = __hfma2(h2(gc2.z), w02, r2);         \
    r2 = __hfma2(h2(gc3.z), w03, r2);                                           \
    __half2 r3 = __hmul2(h2(gc0.w), w00);                                       \
    r3 = __hfma2(h2(gc1.w), w01, r3); r3 = __hfma2(h2(gc2.w), w02, r3);         \
    r3 = __hfma2(h2(gc3.w), w03, r3);                                           \
    uint4 pk;                                                                   \
    pk.x = __builtin_bit_cast(uint32_t, r0);                                    \
    pk.y = __builtin_bit_cast(uint32_t, r1);                                    \
    pk.z = __builtin_bit_cast(uint32_t, r2);                                    \
    pk.w = __builtin_bit_cast(uint32_t, r3);                                    \
    *(uint4*)((ATP) + aw0) = pk;                                                \
  }

#define COMPUTE(ATP, BS)                                                        \
  {                                                                             \
    _Pragma("unroll")                                                           \
    for (int m = 0; m < 2; ++m) {                                               \
      half8 af0 = *(const half8*)((ATP) + a_base + m * 1024 + grp0 * 8);        \
      half8 af1 = *(const half8*)((ATP) + a_base + m * 1024 + grp1 * 8);        \
      _Pragma("unroll")                                                         \
      for (int nn = 0; nn < 4; ++nn) {                                          \
        acc[m][nn] = __builtin_amdgcn_mfma_f32_16x16x32_f16(af0, BS[0][nn], acc[m][nn], 0, 0, 0); \
        acc[m][nn] = __builtin_amdgcn_mfma_f32_16x16x32_f16(af1, BS[1][nn], acc[m][nn], 0, 0, 0); \
      }                                                                         \
    }                                                                           \
  }

  // prologue: tap 0 setup + stage chunk 0 into At[0]
  {
    uint4 ce0 = *(const uint4*)cb;
    TAPSETUP_R(ce0)
  }
  AGATHER(0)
  AMATH(&At[0][0])
  __syncthreads();

  for (int tap = 0; tap < 9; ++tap) {
#pragma unroll
    for (int cc = 0; cc < 4; ++cc) {
      const int t = tap * 4 + cc;
      // B(t) for this chunk's MFMAs (contiguous; L1/L2-hot; single buffer)
      BLOADR(t, bC)
      // issue next chunk's gathers before compute (T14 issue-early)
      if (t < 35) {
        if (cc == 2 && tap < 8) cn = *(const uint4*)(cb + (tap + 1) * 32768);
        if (cc == 3) TAPSETUP_R(cn)
        AGATHER(t + 1)
      }
      // compute chunk t (MFMA waits only on B + af ds_reads, not gathers)
      if (cc & 1) { COMPUTE(&At[1][0], bC) } else { COMPUTE(&At[0][0], bC) }
      // finish next chunk's staging (gathers have landed under the MFMAs)
      if (t < 35) {
        if (cc & 1) { AMATH(&At[0][0]) } else { AMATH(&At[1][0]) }
      }
      __syncthreads();   // At swap ordered; all loads drained
    }
  }

  // ---- epilogue: C/D layout col=lane&15(oc), row=quad*4+reg(ow) ----
  float* outp = out + (size_t)bn * 256 * 4096 + (size_t)oh * 64;
#pragma unroll
  for (int m = 0; m < 2; ++m) {
    int ow0 = wrow * 32 + m * 16 + quad * 4;
#pragma unroll
    for (int nn = 0; nn < 4; ++nn) {
      int oc = wcol * 64 + nn * 16 + mrow;
      *(f32x4*)(outp + (size_t)oc * 4096 + ow0) = acc[m][nn];
    }
  }
#undef BLOADR
#undef TAPSETUP_R
#undef AGATHER
#undef AMATH
#undef COMPUTE
}

extern "C" void kernel_launch(void* const* d_in, const int* in_sizes, int n_in,
                              void* d_out, int out_size, void* d_ws, size_t ws_size,
                              hipStream_t stream) {
  (void)in_sizes; (void)n_in; (void)out_size; (void)ws_size;
  const float* x      = (const float*)d_in[0];
  const float* offset = (const float*)d_in[1];
  const float* weight = (const float*)d_in[2];
  float* out = (float*)d_out;

  unsigned short* xb     = (unsigned short*)d_ws;                        // 16.78 MB
  unsigned short* w3s    = xb + (size_t)8 * 64 * 64 * 256;               // +1.18 MB
  unsigned short* coords = w3s + (size_t)36 * 16384;                     // +4.72 MB

  prep_all_kernel<<<5504, 256, 0, stream>>>(x, weight, offset, xb, w3s, coords);
  deform_mfma_kernel<<<512, 512, 0, stream>>>(xb, coords, w3s, out);
}

// Round 6
// 150.662 us; speedup vs baseline: 1.3137x; 1.0291x over previous
//
#include <hip/hip_runtime.h>
#include <hip/hip_fp16.h>
#include <stdint.h>

// deform_conv2d: N=8, C=256, H=W=64, OC=256, 3x3, stride=1, pad=1 -> OH=OW=64
// im2col-fused MFMA GEMM. M=32768 (n,oh,ow), N=256 oc, K=2304 (kd = k*256+c).
// R12: counted barrier (T3/T4). Five schedules all pinned at MfmaUtil ~20-22%
//   with wall ~= SUM of pipes; the invariant was __syncthreads' vmcnt(0)
//   drain x36 forcing every gather/B L2 round-trip to complete per chunk.
//   Now: barrier = s_waitcnt lgkmcnt(0) + raw s_barrier (ds_write/ds_read
//   ordering only); B-loads and A-gathers live in REGISTERS and stay in
//   flight across barriers (data-dep waits only, compiler-inserted).
//   B double-buffered one chunk ahead (R9: no spill at honest bounds).
//   256-thread blocks (tile 32 rows x 256 oc, 1024 blocks, At 2x4KB):
//   VGPR ~140 -> 3 blocks/CU (launch_bounds(256,3)), 3 independent barrier
//   groups per CU for real phase diversity. T5 setprio around MFMA cluster.

typedef _Float16 half8 __attribute__((ext_vector_type(8)));
typedef float f32x4 __attribute__((ext_vector_type(4)));

__device__ __forceinline__ __half2 h2(uint32_t u) {
  return __builtin_bit_cast(__half2, u);
}
__device__ __forceinline__ uint32_t packh2f(float a, float b) {
  return __builtin_bit_cast(uint32_t, __floats2half2_rn(a, b));
}
__device__ __forceinline__ __half2 duplo(uint32_t u) {
  return __half2half2(__builtin_bit_cast(__half, (unsigned short)(u & 0xffffu)));
}
__device__ __forceinline__ __half2 duphi(uint32_t u) {
  return __half2half2(__builtin_bit_cast(__half, (unsigned short)(u >> 16)));
}

// ---- merged prep: [0,2048) x NCHW fp32 -> NHWC f16
//                   [2048,4352) weights -> wave-contiguous f16 panels
//                   [4352,5504) offsets -> packed coords {4 x f16 w, 4 x u16 pix}
__global__ __launch_bounds__(256) void prep_all_kernel(
    const float* __restrict__ x, const float* __restrict__ w,
    const float* __restrict__ offset,
    unsigned short* __restrict__ xb, unsigned short* __restrict__ w3s,
    unsigned short* __restrict__ coords) {
  __shared__ float tile[64][65];
  int tid = threadIdx.x;
  if (blockIdx.x < 2048) {
    int bn   = blockIdx.x >> 8;
    int rem  = blockIdx.x & 255;
    int y    = rem >> 2;
    int cblk = rem & 3;
    const float* src = x + ((size_t)(bn * 256 + cblk * 64)) * 4096 + y * 64;
#pragma unroll
    for (int i = 0; i < 4; ++i) {
      int u  = i * 256 + tid;
      int cl = u >> 4;
      int xs = (u & 15) * 4;
      float4 v = *(const float4*)(src + cl * 4096 + xs);
      tile[cl][xs] = v.x; tile[cl][xs + 1] = v.y;
      tile[cl][xs + 2] = v.z; tile[cl][xs + 3] = v.w;
    }
    __syncthreads();
    unsigned short* dst = xb + ((size_t)(bn * 64 + y) * 64) * 256 + cblk * 64;
#pragma unroll
    for (int i = 0; i < 8; ++i) {
      int v2  = i * 256 + tid;
      int xc  = v2 >> 5;
      int cl2 = (v2 & 31) * 2;
      *(uint32_t*)(dst + xc * 256 + cl2) = packh2f(tile[cl2][xc], tile[cl2 + 1][xc]);
    }
  } else if (blockIdx.x < 4352) {
    // w3s layout: chunk t (16384 shorts) = [wcol(4)][nn(4)][ks(2)][lane(64)][e(8)]
    int idx = (blockIdx.x - 2048) * 256 + tid;   // < 589824
    int t    = idx >> 14;
    int r2   = idx & 16383;
    int e    = r2 & 7;
    int lane = (r2 >> 3) & 63;
    int ks   = (r2 >> 9) & 1;
    int nn   = (r2 >> 10) & 3;
    int wcol = (r2 >> 12) & 3;
    int oc = wcol * 64 + nn * 16 + (lane & 15);
    int kk = (ks * 4 + (lane >> 4)) * 8 + e;
    int c  = (t & 3) * 64 + kk;
    int k  = t >> 2;
    w3s[idx] = __builtin_bit_cast(unsigned short, __float2half(w[(oc * 256 + c) * 9 + k]));
  } else {
    int idx = (blockIdx.x - 4352) * 256 + tid;   // < 294912
    int ow  = idx & 63;
    int oh  = (idx >> 6) & 63;
    int r   = idx >> 12;          // bn*9 + k
    int k   = r % 9;
    int bn  = r / 9;
    int ky = k / 3 - 1;
    int kx = k % 3 - 1;
    float offy = offset[((bn * 18 + 2 * k    ) * 64 + oh) * 64 + ow];
    float offx = offset[((bn * 18 + 2 * k + 1) * 64 + oh) * 64 + ow];
    float y = (float)(oh + ky) + offy;
    float x2 = (float)(ow + kx) + offx;
    float y0f = floorf(y), x0f = floorf(x2);
    float fy = y - y0f, fx = x2 - x0f;
    int y0 = (int)y0f, x0 = (int)x0f;
    int y1 = y0 + 1, x1 = x0 + 1;
    float vy0 = (y0 >= 0 && y0 <= 63) ? 1.0f : 0.0f;
    float vy1 = (y1 >= 0 && y1 <= 63) ? 1.0f : 0.0f;
    float vx0 = (x0 >= 0 && x0 <= 63) ? 1.0f : 0.0f;
    float vx1 = (x1 >= 0 && x1 <= 63) ? 1.0f : 0.0f;
    float wy0 = (1.0f - fy) * vy0, wy1 = fy * vy1;
    float wx0 = (1.0f - fx) * vx0, wx1 = fx * vx1;
    int y0c = min(max(y0, 0), 63), y1c = min(max(y1, 0), 63);
    int x0c = min(max(x0, 0), 63), x1c = min(max(x1, 0), 63);
    unsigned short ent[8];
    ent[0] = __builtin_bit_cast(unsigned short, __float2half(wy0 * wx0));
    ent[1] = __builtin_bit_cast(unsigned short, __float2half(wy0 * wx1));
    ent[2] = __builtin_bit_cast(unsigned short, __float2half(wy1 * wx0));
    ent[3] = __builtin_bit_cast(unsigned short, __float2half(wy1 * wx1));
    ent[4] = (unsigned short)(y0c * 64 + x0c);
    ent[5] = (unsigned short)(y0c * 64 + x1c);
    ent[6] = (unsigned short)(y1c * 64 + x0c);
    ent[7] = (unsigned short)(y1c * 64 + x1c);
    *(uint4*)(coords + (size_t)idx * 8) = *(const uint4*)ent;
  }
}

// ---- main: 1024 blocks x 256 threads; tile 32 rows x 256 oc; wave 32x64 ----
__global__ __launch_bounds__(256, 3) void deform_mfma_kernel(
    const unsigned short* __restrict__ xb,      // NHWC f16
    const unsigned short* __restrict__ coords,  // packed coord entries
    const unsigned short* __restrict__ w3s,     // wave-contiguous panels f16
    float* __restrict__ out) {                  // (8, 256, 64, 64) fp32
  // A-tile only; double-buffered, XOR group swizzle (no pad). 8 KB total.
  __shared__ __align__(16) unsigned short At[2][32 * 64];

  int bn  = blockIdx.x & 7;      // XCD swizzle
  int rem = blockIdx.x >> 3;     // 0..127
  int oh  = rem >> 1;            // 0..63
  int owh = rem & 1;             // ow half: rows owh*32 .. owh*32+31

  int tid  = threadIdx.x;
  int wcol = tid >> 6;           // wave 0..3 -> 64-oc quarter
  int lane = tid & 63;
  int mrow = lane & 15;
  int quad = lane >> 4;

  // staging identity: one thread = one (row, 8-ch group) unit (32x8 = 256)
  int srow = tid >> 3;           // 0..31
  int sg   = tid & 7;

  const char* xbc = (const char*)(xb + (size_t)bn * (64 * 64 * 256));
  const unsigned short* cb =
      coords + ((size_t)((bn * 9) * 64 + oh) * 64 + owh * 32 + srow) * 8;

  int aw0  = srow * 64 + ((sg ^ (srow & 7)) * 8);   // XOR-swizzled slot (shorts)
  int grp0 = quad ^ (mrow & 7);                     // ks=0 A frag group
  int grp1 = (4 + quad) ^ (mrow & 7);               // ks=1 A frag group
  int a_base = mrow * 64;                           // + m*1024 (shorts)
  int b_off  = wcol * 8192 + lane * 16;             // bytes; + (nn*2+ks)*1024

  f32x4 acc[2][4] = {};
  half8 bA[2][4], bB[2][4];

  __half2 w00, w01, w02, w03;
  uint32_t o00, o01, o02, o03;
  uint4 cn, gc0, gc1, gc2, gc3;

  // counted barrier: order LDS ops only; vmcnt stays in flight (T4)
#define CBAR()                                                                  \
  {                                                                             \
    asm volatile("s_waitcnt lgkmcnt(0)" ::: "memory");                          \
    __builtin_amdgcn_s_barrier();                                               \
    asm volatile("" ::: "memory");                                              \
  }

  // B frags straight from w3s: each load = contiguous 1 KB across the wave
#define BLOADR(TT, BS)                                                          \
  {                                                                             \
    const char* wp = (const char*)w3s + (size_t)(TT) * 32768 + b_off;           \
    _Pragma("unroll")                                                           \
    for (int nn = 0; nn < 4; ++nn) {                                            \
      BS[0][nn] = *(const half8*)(wp + (nn * 2 + 0) * 1024);                    \
      BS[1][nn] = *(const half8*)(wp + (nn * 2 + 1) * 1024);                    \
    }                                                                           \
  }

#define TAPSETUP_R(CE)                                                          \
  {                                                                             \
    w00 = duplo((CE).x); w01 = duphi((CE).x);                                   \
    w02 = duplo((CE).y); w03 = duphi((CE).y);                                   \
    o00 = (((CE).z & 0xffffu) << 9) + sg * 16;                                  \
    o01 = (((CE).z >> 16) << 9) + sg * 16;                                      \
    o02 = (((CE).w & 0xffffu) << 9) + sg * 16;                                  \
    o03 = (((CE).w >> 16) << 9) + sg * 16;                                      \
  }

  // issue the 4 corner gathers (latency hides under COMPUTE + barrier)
#define AGATHER(TT)                                                             \
  {                                                                             \
    gc0 = *(const uint4*)(xbc + o00 + ((TT) & 3) * 128);                        \
    gc1 = *(const uint4*)(xbc + o01 + ((TT) & 3) * 128);                        \
    gc2 = *(const uint4*)(xbc + o02 + ((TT) & 3) * 128);                        \
    gc3 = *(const uint4*)(xbc + o03 + ((TT) & 3) * 128);                        \
  }

  // packed-f16 bilinear combine + LDS write (after COMPUTE, before barrier)
#define AMATH(ATP)                                                              \
  {                                                                             \
    __half2 r0 = __hmul2(h2(gc0.x), w00);                                       \
    r0 = __hfma2(h2(gc1.x), w01, r0); r0 = __hfma2(h2(gc2.x), w02, r0);         \
    r0 = __hfma2(h2(gc3.x), w03, r0);                                           \
    __half2 r1 = __hmul2(h2(gc0.y), w00);                                       \
    r1 = __hfma2(h2(gc1.y), w01, r1); r1 = __hfma2(h2(gc2.y), w02, r1);         \
    r1 = __hfma2(h2(gc3.y), w03, r1);                                           \
    __half2 r2 = __hmul2(h2(gc0.z), w00);                                       \
    r2 = __hfma2(h2(gc1.z), w01, r2); r2 = __hfma2(h2(gc2.z), w02, r2);         \
    r2 = __hfma2(h2(gc3.z), w03, r2);                                           \
    __half2 r3 = __hmul2(h2(gc0.w), w00);                                       \
    r3 = __hfma2(h2(gc1.w), w01, r3); r3 = __hfma2(h2(gc2.w), w02, r3);         \
    r3 = __hfma2(h2(gc3.w), w03, r3);                                           \
    uint4 pk;                                                                   \
    pk.x = __builtin_bit_cast(uint32_t, r0);                                    \
    pk.y = __builtin_bit_cast(uint32_t, r1);                                    \
    pk.z = __builtin_bit_cast(uint32_t, r2);                                    \
    pk.w = __builtin_bit_cast(uint32_t, r3);                                    \
    *(uint4*)((ATP) + aw0) = pk;                                                \
  }

#define COMPUTE(ATP, BS)                                                        \
  {                                                                             \
    half8 af00 = *(const half8*)((ATP) + a_base + grp0 * 8);                    \
    half8 af01 = *(const half8*)((ATP) + a_base + grp1 * 8);                    \
    half8 af10 = *(const half8*)((ATP) + a_base + 1024 + grp0 * 8);             \
    half8 af11 = *(const half8*)((ATP) + a_base + 1024 + grp1 * 8);             \
    __builtin_amdgcn_s_setprio(1);                                              \
    _Pragma("unroll")                                                           \
    for (int nn = 0; nn < 4; ++nn) {                                            \
      acc[0][nn] = __builtin_amdgcn_mfma_f32_16x16x32_f16(af00, BS[0][nn], acc[0][nn], 0, 0, 0); \
      acc[0][nn] = __builtin_amdgcn_mfma_f32_16x16x32_f16(af01, BS[1][nn], acc[0][nn], 0, 0, 0); \
      acc[1][nn] = __builtin_amdgcn_mfma_f32_16x16x32_f16(af10, BS[0][nn], acc[1][nn], 0, 0, 0); \
      acc[1][nn] = __builtin_amdgcn_mfma_f32_16x16x32_f16(af11, BS[1][nn], acc[1][nn], 0, 0, 0); \
    }                                                                           \
    __builtin_amdgcn_s_setprio(0);                                              \
  }

  // prologue: tap 0 setup + B(0) + stage chunk 0 into At[0]
  {
    uint4 ce0 = *(const uint4*)cb;
    TAPSETUP_R(ce0)
  }
  BLOADR(0, bA)
  AGATHER(0)
  AMATH(&At[0][0])
  CBAR()

  for (int tap = 0; tap < 9; ++tap) {
#pragma unroll
    for (int cc = 0; cc < 4; ++cc) {
      const int t = tap * 4 + cc;
      // ---- issue next chunk's loads first (stay in flight across CBAR) ----
      if (t < 35) {
        if (cc & 1) { BLOADR(t + 1, bA) } else { BLOADR(t + 1, bB) }
        if (cc == 2 && tap < 8) cn = *(const uint4*)(cb + (tap + 1) * 32768);
        if (cc == 3) TAPSETUP_R(cn)
        AGATHER(t + 1)
      }
      // ---- compute chunk t (af ds_reads + 16 MFMAs, setprio-wrapped) ----
      if (cc & 1) { COMPUTE(&At[1][0], bB) } else { COMPUTE(&At[0][0], bA) }
      // ---- finish next chunk's A staging (gathers landed under MFMAs) ----
      if (t < 35) {
        if (cc & 1) { AMATH(&At[0][0]) } else { AMATH(&At[1][0]) }
        CBAR()   // orders ds ops only; B/gather loads remain in flight
      }
    }
  }

  // ---- epilogue: C/D layout col=lane&15(oc), row=quad*4+reg(ow) ----
  float* outp = out + (size_t)bn * 256 * 4096 + (size_t)oh * 64 + owh * 32;
#pragma unroll
  for (int m = 0; m < 2; ++m) {
    int ow0 = m * 16 + quad * 4;
#pragma unroll
    for (int nn = 0; nn < 4; ++nn) {
      int oc = wcol * 64 + nn * 16 + mrow;
      *(f32x4*)(outp + (size_t)oc * 4096 + ow0) = acc[m][nn];
    }
  }
#undef CBAR
#undef BLOADR
#undef TAPSETUP_R
#undef AGATHER
#undef AMATH
#undef COMPUTE
}

extern "C" void kernel_launch(void* const* d_in, const int* in_sizes, int n_in,
                              void* d_out, int out_size, void* d_ws, size_t ws_size,
                              hipStream_t stream) {
  (void)in_sizes; (void)n_in; (void)out_size; (void)ws_size;
  const float* x      = (const float*)d_in[0];
  const float* offset = (const float*)d_in[1];
  const float* weight = (const float*)d_in[2];
  float* out = (float*)d_out;

  unsigned short* xb     = (unsigned short*)d_ws;                        // 16.78 MB
  unsigned short* w3s    = xb + (size_t)8 * 64 * 64 * 256;               // +1.18 MB
  unsigned short* coords = w3s + (size_t)36 * 16384;                     // +4.72 MB

  prep_all_kernel<<<5504, 256, 0, stream>>>(x, weight, offset, xb, w3s, coords);
  deform_mfma_kernel<<<1024, 256, 0, stream>>>(xb, coords, w3s, out);
}

// Round 7
// 140.723 us; speedup vs baseline: 1.4065x; 1.0706x over previous
//
#include <hip/hip_runtime.h>
#include <hip/hip_fp16.h>
#include <stdint.h>

// deform_conv2d: N=8, C=256, H=W=64, OC=256, 3x3, stride=1, pad=1 -> OH=OW=64
// im2col-fused MFMA GEMM. M=32768 (n,oh,ow), N=256 oc, K=2304 (kd = k*256+c).
// R13: R9 tile (128x256, 1 block/CU, TA-minimal: B re-read 2x not 4x) +
//   R12 counted barrier (lgkmcnt-only) + ISSUE-ORDER FIX. R12's bug: B loads
//   issued BEFORE gathers => AMATH's use of the (newest) gathers forced
//   vmcnt(0), draining B too -- nothing was ever in flight across the
//   barrier, explaining the 7-schedule MfmaUtil~21% plateau. Now gathers
//   issue first: COMPUTE(t) waits vmcnt(16) for prev B only; AMATH(t+1)
//   waits vmcnt(8) (gathers only), so B(t+1) crosses the barrier in flight.
//   B double-buffered in regs at honest launch_bounds(512,2) (R9: no spill).
//   LDS = At only 2x16KB, XOR swizzle. setprio around MFMA cluster.

typedef _Float16 half8 __attribute__((ext_vector_type(8)));
typedef float f32x4 __attribute__((ext_vector_type(4)));

__device__ __forceinline__ __half2 h2(uint32_t u) {
  return __builtin_bit_cast(__half2, u);
}
__device__ __forceinline__ uint32_t packh2f(float a, float b) {
  return __builtin_bit_cast(uint32_t, __floats2half2_rn(a, b));
}
__device__ __forceinline__ __half2 duplo(uint32_t u) {
  return __half2half2(__builtin_bit_cast(__half, (unsigned short)(u & 0xffffu)));
}
__device__ __forceinline__ __half2 duphi(uint32_t u) {
  return __half2half2(__builtin_bit_cast(__half, (unsigned short)(u >> 16)));
}

// ---- merged prep: [0,2048) x NCHW fp32 -> NHWC f16
//                   [2048,4352) weights -> wave-contiguous f16 panels
//                   [4352,5504) offsets -> packed coords {4 x f16 w, 4 x u16 pix}
__global__ __launch_bounds__(256) void prep_all_kernel(
    const float* __restrict__ x, const float* __restrict__ w,
    const float* __restrict__ offset,
    unsigned short* __restrict__ xb, unsigned short* __restrict__ w3s,
    unsigned short* __restrict__ coords) {
  __shared__ float tile[64][65];
  int tid = threadIdx.x;
  if (blockIdx.x < 2048) {
    int bn   = blockIdx.x >> 8;
    int rem  = blockIdx.x & 255;
    int y    = rem >> 2;
    int cblk = rem & 3;
    const float* src = x + ((size_t)(bn * 256 + cblk * 64)) * 4096 + y * 64;
#pragma unroll
    for (int i = 0; i < 4; ++i) {
      int u  = i * 256 + tid;
      int cl = u >> 4;
      int xs = (u & 15) * 4;
      float4 v = *(const float4*)(src + cl * 4096 + xs);
      tile[cl][xs] = v.x; tile[cl][xs + 1] = v.y;
      tile[cl][xs + 2] = v.z; tile[cl][xs + 3] = v.w;
    }
    __syncthreads();
    unsigned short* dst = xb + ((size_t)(bn * 64 + y) * 64) * 256 + cblk * 64;
#pragma unroll
    for (int i = 0; i < 8; ++i) {
      int v2  = i * 256 + tid;
      int xc  = v2 >> 5;
      int cl2 = (v2 & 31) * 2;
      *(uint32_t*)(dst + xc * 256 + cl2) = packh2f(tile[cl2][xc], tile[cl2 + 1][xc]);
    }
  } else if (blockIdx.x < 4352) {
    // w3s layout: chunk t (16384 shorts) = [wcol(4)][nn(4)][ks(2)][lane(64)][e(8)]
    int idx = (blockIdx.x - 2048) * 256 + tid;   // < 589824
    int t    = idx >> 14;
    int r2   = idx & 16383;
    int e    = r2 & 7;
    int lane = (r2 >> 3) & 63;
    int ks   = (r2 >> 9) & 1;
    int nn   = (r2 >> 10) & 3;
    int wcol = (r2 >> 12) & 3;
    int oc = wcol * 64 + nn * 16 + (lane & 15);
    int kk = (ks * 4 + (lane >> 4)) * 8 + e;
    int c  = (t & 3) * 64 + kk;
    int k  = t >> 2;
    w3s[idx] = __builtin_bit_cast(unsigned short, __float2half(w[(oc * 256 + c) * 9 + k]));
  } else {
    int idx = (blockIdx.x - 4352) * 256 + tid;   // < 294912
    int ow  = idx & 63;
    int oh  = (idx >> 6) & 63;
    int r   = idx >> 12;          // bn*9 + k
    int k   = r % 9;
    int bn  = r / 9;
    int ky = k / 3 - 1;
    int kx = k % 3 - 1;
    float offy = offset[((bn * 18 + 2 * k    ) * 64 + oh) * 64 + ow];
    float offx = offset[((bn * 18 + 2 * k + 1) * 64 + oh) * 64 + ow];
    float y = (float)(oh + ky) + offy;
    float x2 = (float)(ow + kx) + offx;
    float y0f = floorf(y), x0f = floorf(x2);
    float fy = y - y0f, fx = x2 - x0f;
    int y0 = (int)y0f, x0 = (int)x0f;
    int y1 = y0 + 1, x1 = x0 + 1;
    float vy0 = (y0 >= 0 && y0 <= 63) ? 1.0f : 0.0f;
    float vy1 = (y1 >= 0 && y1 <= 63) ? 1.0f : 0.0f;
    float vx0 = (x0 >= 0 && x0 <= 63) ? 1.0f : 0.0f;
    float vx1 = (x1 >= 0 && x1 <= 63) ? 1.0f : 0.0f;
    float wy0 = (1.0f - fy) * vy0, wy1 = fy * vy1;
    float wx0 = (1.0f - fx) * vx0, wx1 = fx * vx1;
    int y0c = min(max(y0, 0), 63), y1c = min(max(y1, 0), 63);
    int x0c = min(max(x0, 0), 63), x1c = min(max(x1, 0), 63);
    unsigned short ent[8];
    ent[0] = __builtin_bit_cast(unsigned short, __float2half(wy0 * wx0));
    ent[1] = __builtin_bit_cast(unsigned short, __float2half(wy0 * wx1));
    ent[2] = __builtin_bit_cast(unsigned short, __float2half(wy1 * wx0));
    ent[3] = __builtin_bit_cast(unsigned short, __float2half(wy1 * wx1));
    ent[4] = (unsigned short)(y0c * 64 + x0c);
    ent[5] = (unsigned short)(y0c * 64 + x1c);
    ent[6] = (unsigned short)(y1c * 64 + x0c);
    ent[7] = (unsigned short)(y1c * 64 + x1c);
    *(uint4*)(coords + (size_t)idx * 8) = *(const uint4*)ent;
  }
}

// ---- main: 256 blocks x 512 threads; tile 128 rows x 256 oc; wave 64x64 ----
__global__ __launch_bounds__(512, 2) void deform_mfma_kernel(
    const unsigned short* __restrict__ xb,      // NHWC f16
    const unsigned short* __restrict__ coords,  // packed coord entries
    const unsigned short* __restrict__ w3s,     // wave-contiguous panels f16
    float* __restrict__ out) {                  // (8, 256, 64, 64) fp32
  // A-tile only; double-buffered, XOR group swizzle (no pad). 32 KB total.
  __shared__ __align__(16) unsigned short At[2][128 * 64];

  int bn  = blockIdx.x & 7;      // XCD swizzle
  int ohp = blockIdx.x >> 3;     // 0..31 -> oh rows {2*ohp, 2*ohp+1}
  int tid = threadIdx.x;

  int w    = tid >> 6;            // wave 0..7
  int lane = tid & 63;
  int wrow = w & 1;               // 64-row half
  int wcol = w >> 1;              // 64-oc quarter
  int mrow = lane & 15;
  int quad = lane >> 4;

  // staging identity: thread = rows {srow, srow+64} x channel-group sg
  int srow = tid >> 3;             // 0..63
  int sg   = tid & 7;

  const char* xbc = (const char*)(xb + (size_t)bn * (64 * 64 * 256));
  const unsigned short* cb0 = coords + ((size_t)((bn * 9) * 64 + ohp * 2) * 64 + srow) * 8;
  const unsigned short* cb1 = cb0 + 512;   // next oh row

  int aw0  = srow * 64 + ((sg ^ (srow & 7)) * 8);   // shorts; unit2 at +4096
  int grp0 = quad ^ (mrow & 7);                     // ks=0 A frag group
  int grp1 = (4 + quad) ^ (mrow & 7);               // ks=1 A frag group
  int a_base = (wrow * 64 + mrow) * 64;             // + m*1024 (shorts)
  int b_off  = wcol * 8192 + lane * 16;             // bytes; + (nn*2+ks)*1024

  f32x4 acc[4][4] = {};
  half8 bA[2][4], bB[2][4];

  __half2 w00, w01, w02, w03, w10, w11, w12, w13;
  uint32_t o00, o01, o02, o03, o10, o11, o12, o13;
  uint4 cn0, cn1;
  uint4 ga0, ga1, ga2, ga3, gb0, gb1, gb2, gb3;   // in-flight corner gathers

  // counted barrier: order LDS ops only; vmcnt stays in flight (T4)
#define CBAR()                                                                  \
  {                                                                             \
    asm volatile("s_waitcnt lgkmcnt(0)" ::: "memory");                          \
    __builtin_amdgcn_s_barrier();                                               \
    asm volatile("" ::: "memory");                                              \
  }

  // B frags straight from w3s: each load = contiguous 1 KB across the wave
#define BLOADR(TT, BS)                                                          \
  {                                                                             \
    const char* wp = (const char*)w3s + (size_t)(TT) * 32768 + b_off;           \
    _Pragma("unroll")                                                           \
    for (int nn = 0; nn < 4; ++nn) {                                            \
      BS[0][nn] = *(const half8*)(wp + (nn * 2 + 0) * 1024);                    \
      BS[1][nn] = *(const half8*)(wp + (nn * 2 + 1) * 1024);                    \
    }                                                                           \
  }

#define TAPSETUP_R(CE0, CE1)                                                    \
  {                                                                             \
    w00 = duplo((CE0).x); w01 = duphi((CE0).x);                                 \
    w02 = duplo((CE0).y); w03 = duphi((CE0).y);                                 \
    o00 = (((CE0).z & 0xffffu) << 9) + sg * 16;                                 \
    o01 = (((CE0).z >> 16) << 9) + sg * 16;                                     \
    o02 = (((CE0).w & 0xffffu) << 9) + sg * 16;                                 \
    o03 = (((CE0).w >> 16) << 9) + sg * 16;                                     \
    w10 = duplo((CE1).x); w11 = duphi((CE1).x);                                 \
    w12 = duplo((CE1).y); w13 = duphi((CE1).y);                                 \
    o10 = (((CE1).z & 0xffffu) << 9) + sg * 16;                                 \
    o11 = (((CE1).z >> 16) << 9) + sg * 16;                                     \
    o12 = (((CE1).w & 0xffffu) << 9) + sg * 16;                                 \
    o13 = (((CE1).w >> 16) << 9) + sg * 16;                                     \
  }

  // issue the 8 corner gathers (2 units); OLDEST vmem of the iteration
#define AGATHER(TT)                                                             \
  {                                                                             \
    ga0 = *(const uint4*)(xbc + o00 + ((TT) & 3) * 128);                        \
    ga1 = *(const uint4*)(xbc + o01 + ((TT) & 3) * 128);                        \
    ga2 = *(const uint4*)(xbc + o02 + ((TT) & 3) * 128);                        \
    ga3 = *(const uint4*)(xbc + o03 + ((TT) & 3) * 128);                        \
    gb0 = *(const uint4*)(xbc + o10 + ((TT) & 3) * 128);                        \
    gb1 = *(const uint4*)(xbc + o11 + ((TT) & 3) * 128);                        \
    gb2 = *(const uint4*)(xbc + o12 + ((TT) & 3) * 128);                        \
    gb3 = *(const uint4*)(xbc + o13 + ((TT) & 3) * 128);                        \
  }

  // packed-f16 bilinear combine + LDS writes; waits only on the gathers
#define AMATH(ATP)                                                              \
  {                                                                             \
    __half2 r0 = __hmul2(h2(ga0.x), w00);                                       \
    r0 = __hfma2(h2(ga1.x), w01, r0); r0 = __hfma2(h2(ga2.x), w02, r0);         \
    r0 = __hfma2(h2(ga3.x), w03, r0);                                           \
    __half2 r1 = __hmul2(h2(ga0.y), w00);                                       \
    r1 = __hfma2(h2(ga1.y), w01, r1); r1 = __hfma2(h2(ga2.y), w02, r1);         \
    r1 = __hfma2(h2(ga3.y), w03, r1);                                           \
    __half2 r2 = __hmul2(h2(ga0.z), w00);                                       \
    r2 = __hfma2(h2(ga1.z), w01, r2); r2 = __hfma2(h2(ga2.z), w02, r2);         \
    r2 = __hfma2(h2(ga3.z), w03, r2);                                           \
    __half2 r3 = __hmul2(h2(ga0.w), w00);                                       \
    r3 = __hfma2(h2(ga1.w), w01, r3); r3 = __hfma2(h2(ga2.w), w02, r3);         \
    r3 = __hfma2(h2(ga3.w), w03, r3);                                           \
    uint4 pk;                                                                   \
    pk.x = __builtin_bit_cast(uint32_t, r0);                                    \
    pk.y = __builtin_bit_cast(uint32_t, r1);                                    \
    pk.z = __builtin_bit_cast(uint32_t, r2);                                    \
    pk.w = __builtin_bit_cast(uint32_t, r3);                                    \
    *(uint4*)((ATP) + aw0) = pk;                                                \
    __half2 s0 = __hmul2(h2(gb0.x), w10);                                       \
    s0 = __hfma2(h2(gb1.x), w11, s0); s0 = __hfma2(h2(gb2.x), w12, s0);         \
    s0 = __hfma2(h2(gb3.x), w13, s0);                                           \
    __half2 s1 = __hmul2(h2(gb0.y), w10);                                       \
    s1 = __hfma2(h2(gb1.y), w11, s1); s1 = __hfma2(h2(gb2.y), w12, s1);         \
    s1 = __hfma2(h2(gb3.y), w13, s1);                                           \
    __half2 s2 = __hmul2(h2(gb0.z), w10);                                       \
    s2 = __hfma2(h2(gb1.z), w11, s2); s2 = __hfma2(h2(gb2.z), w12, s2);         \
    s2 = __hfma2(h2(gb3.z), w13, s2);                                           \
    __half2 s3 = __hmul2(h2(gb0.w), w10);                                       \
    s3 = __hfma2(h2(gb1.w), w11, s3); s3 = __hfma2(h2(gb2.w), w12, s3);         \
    s3 = __hfma2(h2(gb3.w), w13, s3);                                           \
    uint4 qk;                                                                   \
    qk.x = __builtin_bit_cast(uint32_t, s0);                                    \
    qk.y = __builtin_bit_cast(uint32_t, s1);                                    \
    qk.z = __builtin_bit_cast(uint32_t, s2);                                    \
    qk.w = __builtin_bit_cast(uint32_t, s3);                                    \
    *(uint4*)((ATP) + aw0 + 4096) = qk;                                         \
  }

#define COMPUTE(ATP, BS)                                                        \
  {                                                                             \
    __builtin_amdgcn_s_setprio(1);                                              \
    _Pragma("unroll")                                                           \
    for (int m = 0; m < 4; ++m) {                                               \
      half8 af0 = *(const half8*)((ATP) + a_base + m * 1024 + grp0 * 8);        \
      half8 af1 = *(const half8*)((ATP) + a_base + m * 1024 + grp1 * 8);        \
      _Pragma("unroll")                                                         \
      for (int nn = 0; nn < 4; ++nn) {                                          \
        acc[m][nn] = __builtin_amdgcn_mfma_f32_16x16x32_f16(af0, BS[0][nn], acc[m][nn], 0, 0, 0); \
        acc[m][nn] = __builtin_amdgcn_mfma_f32_16x16x32_f16(af1, BS[1][nn], acc[m][nn], 0, 0, 0); \
      }                                                                         \
    }                                                                           \
    __builtin_amdgcn_s_setprio(0);                                              \
  }

  // prologue: tap 0 setup + gathers(0) + B(0) + stage chunk 0 into At[0]
  {
    uint4 ce0 = *(const uint4*)cb0;
    uint4 ce1 = *(const uint4*)cb1;
    TAPSETUP_R(ce0, ce1)
  }
  AGATHER(0)
  BLOADR(0, bA)
  AMATH(&At[0][0])
  CBAR()

  for (int tap = 0; tap < 9; ++tap) {
#pragma unroll
    for (int cc = 0; cc < 4; ++cc) {
      const int t = tap * 4 + cc;
      // ---- issue next chunk's vmem: gathers FIRST (oldest), B last ----
      if (t < 35) {
        if (cc == 3) TAPSETUP_R(cn0, cn1)   // VALU-only; coords prefetched
        AGATHER(t + 1)
        if (cc == 2 && tap < 8) {
          cn0 = *(const uint4*)(cb0 + (tap + 1) * 32768);
          cn1 = *(const uint4*)(cb1 + (tap + 1) * 32768);
        }
        if (cc & 1) { BLOADR(t + 1, bA) } else { BLOADR(t + 1, bB) }
      }
      // ---- compute chunk t: waits vmcnt for prev-iter B only ----
      if (cc & 1) { COMPUTE(&At[1][0], bB) } else { COMPUTE(&At[0][0], bA) }
      // ---- finish A staging: waits vmcnt(8) (gathers); B stays in flight ----
      if (t < 35) {
        if (cc & 1) { AMATH(&At[0][0]) } else { AMATH(&At[1][0]) }
      }
      CBAR()   // lgkm-only: At swap ordered; B(t+1) crosses in flight
    }
  }

  // ---- epilogue: C/D layout col=lane&15(oc), row=quad*4+reg(ow) ----
  float* outp = out + (size_t)bn * 256 * 4096 + (size_t)(ohp * 2 + wrow) * 64;
#pragma unroll
  for (int m = 0; m < 4; ++m) {
    int ow0 = m * 16 + quad * 4;
#pragma unroll
    for (int nn = 0; nn < 4; ++nn) {
      int oc = wcol * 64 + nn * 16 + mrow;
      *(f32x4*)(outp + (size_t)oc * 4096 + ow0) = acc[m][nn];
    }
  }
#undef CBAR
#undef BLOADR
#undef TAPSETUP_R
#undef AGATHER
#undef AMATH
#undef COMPUTE
}

extern "C" void kernel_launch(void* const* d_in, const int* in_sizes, int n_in,
                              void* d_out, int out_size, void* d_ws, size_t ws_size,
                              hipStream_t stream) {
  (void)in_sizes; (void)n_in; (void)out_size; (void)ws_size;
  const float* x      = (const float*)d_in[0];
  const float* offset = (const float*)d_in[1];
  const float* weight = (const float*)d_in[2];
  float* out = (float*)d_out;

  unsigned short* xb     = (unsigned short*)d_ws;                        // 16.78 MB
  unsigned short* w3s    = xb + (size_t)8 * 64 * 64 * 256;               // +1.18 MB
  unsigned short* coords = w3s + (size_t)36 * 16384;                     // +4.72 MB

  prep_all_kernel<<<5504, 256, 0, stream>>>(x, weight, offset, xb, w3s, coords);
  deform_mfma_kernel<<<256, 512, 0, stream>>>(xb, coords, w3s, out);
}